// Round 12
// baseline (206.019 us; speedup 1.0000x reference)
//
#include <hip/hip_runtime.h>
#include <math.h>

// ---------------------------------------------------------------------------
// GCN: 3x GCNConv (linear) -> mean pool -> linear -> sigmoid.
// Linear-collapse identity (absmax 0.0 through R11):
//   h3 @ lin_w = A(A(A(X u) + s2) + s1) + s0,  u = W1W2W3 lin_w.
// History: R10 cooperative grid.sync = ~50us/sync (cross-XCD) -> reverted.
// R11 = 8 dispatches, 128.0us. R12: (a) fold final into gatherpool via
// last-block-done (device atomics + threadfence; coherent reads via
// atomicAdd(p,0)); (b) 8-edge/thread unroll in bucket passes (latency-bound,
// VALUBusy 0.8% -> MLP is the only intra-kernel lever). 7 dispatches.
// ---------------------------------------------------------------------------

#define SHIFT      8
#define BSZ        256         // nodes per bucket = 1<<SHIFT
#define NB_SCAT    256         // blocks for hist/scatter phases
#define B_SCAT     1024        // threads for hist/scatter
#define B_GATH     1024        // threads for bucket (gather) kernels
#define ROWMASK    0x1FFFFu    // 17 bits for row id (n < 131072)
#define PSLOTS     64          // LDS pool slots per pass-3 block
#define MAXNB      2048        // scan capacity guard

// ---- K1: histogram + in-block scan (Mcnt, Mloc) + coeffs + zero sums ----
__global__ void hist_kernel(const int* __restrict__ col, int E, int tile, int nbuck,
                            unsigned* __restrict__ Mcnt, unsigned* __restrict__ Mloc,
                            const float* __restrict__ W1, const float* __restrict__ b1,
                            const float* __restrict__ W2, const float* __restrict__ b2,
                            const float* __restrict__ W3, const float* __restrict__ b3,
                            const float* __restrict__ lin_w, const float* __restrict__ lin_b,
                            float* __restrict__ coeff,
                            float* __restrict__ sums, float* __restrict__ cnt, int ngraphs,
                            unsigned* __restrict__ done) {
    extern __shared__ unsigned h[];
    __shared__ unsigned tsum[B_SCAT];
    __shared__ float w3l[16], w2l[16];
    int t = threadIdx.x;
    for (int i = t; i < nbuck; i += blockDim.x) h[i] = 0;
    if (blockIdx.x == 0) {
        for (int i = t; i < ngraphs; i += blockDim.x) { sums[i] = 0.f; cnt[i] = 0.f; }
        if (t == 0) *done = 0u;
        if (t < 16) {
            float s = 0.f;
            for (int j = 0; j < 16; ++j) s += W3[t * 16 + j] * lin_w[j];
            w3l[t] = s;
        }
    }
    __syncthreads();
    if (blockIdx.x == 0 && t < 16) {
        float s = 0.f;
        for (int j = 0; j < 16; ++j) s += W2[t * 16 + j] * w3l[j];
        w2l[t] = s;
    }
    __syncthreads();
    if (blockIdx.x == 0) {
        if (t < 4) {
            float s = 0.f;
            for (int j = 0; j < 16; ++j) s += W1[t * 16 + j] * w2l[j];
            coeff[t] = s;
        } else if (t == 4) {
            float s = 0.f;
            for (int j = 0; j < 16; ++j) s += b1[j] * w2l[j];
            coeff[4] = s;
        } else if (t == 5) {
            float s = 0.f;
            for (int j = 0; j < 16; ++j) s += b2[j] * w3l[j];
            coeff[5] = s;
        } else if (t == 6) {
            float s = 0.f;
            for (int j = 0; j < 16; ++j) s += b3[j] * lin_w[j];
            coeff[6] = s;
        } else if (t == 7) {
            coeff[7] = lin_b[0];
        }
    }
    // histogram of this block's tile
    int b = blockIdx.x;
    int s = b * tile, e = min(s + tile, E);          // s multiple of 4
    if (s < e) {
        int nq = (e - s) >> 2;
        const int4* c4 = (const int4*)(col + s);
        for (int q = t; q < nq; q += blockDim.x) {
            int4 c = c4[q];
            atomicAdd(&h[((unsigned)c.x) >> SHIFT], 1u);
            atomicAdd(&h[((unsigned)c.y) >> SHIFT], 1u);
            atomicAdd(&h[((unsigned)c.z) >> SHIFT], 1u);
            atomicAdd(&h[((unsigned)c.w) >> SHIFT], 1u);
        }
        for (int k = s + (nq << 2) + t; k < e; k += blockDim.x)
            atomicAdd(&h[((unsigned)col[k]) >> SHIFT], 1u);
    }
    __syncthreads();
    // in-block exclusive scan of h -> Mloc; counts -> Mcnt
    const int C = MAXNB / B_SCAT;            // 2 elems/thread
    unsigned lv[C];
    unsigned run = 0;
    for (int k = 0; k < C; ++k) {
        int i = t * C + k;
        unsigned x = (i < nbuck) ? h[i] : 0u;
        lv[k] = run; run += x;
    }
    tsum[t] = run;
    __syncthreads();
    for (int off = 1; off < B_SCAT; off <<= 1) {
        unsigned u = (t >= off) ? tsum[t - off] : 0u;
        __syncthreads();
        tsum[t] += u;
        __syncthreads();
    }
    unsigned ex = (t == 0) ? 0u : tsum[t - 1];
    for (int k = 0; k < C; ++k) {
        int i = t * C + k;
        if (i < nbuck) {
            Mcnt[(size_t)b * nbuck + i] = h[i];
            Mloc[(size_t)b * nbuck + i] = ex + lv[k];
        }
    }
}

// ---- K2: per-bin exclusive scan over block counts -> Mpre, binTotal ----
__global__ void scanA_kernel(const unsigned* __restrict__ Mcnt, unsigned* __restrict__ Mpre,
                             unsigned* __restrict__ binTotal, int nbuck) {
    __shared__ unsigned sc[NB_SCAT];
    int b = blockIdx.x;
    int t = threadIdx.x;
    unsigned v = Mcnt[(size_t)t * nbuck + b];
    sc[t] = v;
    __syncthreads();
    for (int off = 1; off < NB_SCAT; off <<= 1) {
        unsigned u = (t >= off) ? sc[t - off] : 0u;
        __syncthreads();
        sc[t] += u;
        __syncthreads();
    }
    Mpre[(size_t)t * nbuck + b] = sc[t] - v;     // exclusive within bin
    if (t == NB_SCAT - 1) binTotal[b] = sc[t];
}

// ---- K3: scatter; tables preloaded, only binTotal scan in-block ----
// pack: row(17b) | col_low(8b)<<17
__global__ void scatter_kernel(const int* __restrict__ row, const int* __restrict__ col,
                               int E, int tile, int nbuck,
                               const unsigned* __restrict__ Mcnt,
                               const unsigned* __restrict__ Mloc,
                               const unsigned* __restrict__ Mpre,
                               const unsigned* __restrict__ binTotal,
                               unsigned* __restrict__ bstart,
                               unsigned* __restrict__ out) {
    extern __shared__ unsigned lds[];
    unsigned* hA    = lds;                   // nbuck  local counts
    unsigned* lofs  = lds + nbuck;           // nbuck  local exclusive offsets
    unsigned* lcur  = lds + 2 * nbuck;       // nbuck  placement cursors
    unsigned* gbase = lds + 3 * nbuck;       // nbuck  global run starts (this block)
    unsigned* tsum  = lds + 4 * nbuck;       // B_SCAT scan workspace
    unsigned* stage = lds + 4 * nbuck + B_SCAT; // tile staged packed words
    int t = threadIdx.x, j = blockIdx.x;
    // load local tables
    for (int i = t; i < nbuck; i += blockDim.x) {
        unsigned c = Mcnt[(size_t)j * nbuck + i];
        unsigned l = Mloc[(size_t)j * nbuck + i];
        hA[i] = c; lofs[i] = l; lcur[i] = l;
    }
    // binTotal exclusive scan -> gbase (+ bstart publish from block 0)
    const int C = MAXNB / B_SCAT;            // 2 elems/thread
    unsigned lv[C];
    unsigned run = 0;
    for (int k = 0; k < C; ++k) {
        int i = t * C + k;
        unsigned x = (i < nbuck) ? binTotal[i] : 0u;
        lv[k] = run; run += x;
    }
    tsum[t] = run;
    __syncthreads();
    for (int off = 1; off < B_SCAT; off <<= 1) {
        unsigned u = (t >= off) ? tsum[t - off] : 0u;
        __syncthreads();
        tsum[t] += u;
        __syncthreads();
    }
    unsigned ex = (t == 0) ? 0u : tsum[t - 1];
    for (int k = 0; k < C; ++k) {
        int i = t * C + k;
        if (i < nbuck) {
            unsigned bb = ex + lv[k];
            gbase[i] = bb + Mpre[(size_t)j * nbuck + i];
            if (j == 0) bstart[i] = bb;
        }
    }
    if (j == 0 && t == 0) bstart[nbuck] = (unsigned)E;
    __syncthreads();
    // placement into stage (LDS random write)
    int s = j * tile, e = min(s + tile, E);
    if (s < e) {
        int nq = (e - s) >> 2;
        const int4* r4 = (const int4*)(row + s);
        const int4* c4 = (const int4*)(col + s);
        for (int q = t; q < nq; q += blockDim.x) {
            int4 r = r4[q];
            int4 c = c4[q];
            unsigned p0 = atomicAdd(&lcur[((unsigned)c.x) >> SHIFT], 1u);
            unsigned p1 = atomicAdd(&lcur[((unsigned)c.y) >> SHIFT], 1u);
            unsigned p2 = atomicAdd(&lcur[((unsigned)c.z) >> SHIFT], 1u);
            unsigned p3 = atomicAdd(&lcur[((unsigned)c.w) >> SHIFT], 1u);
            stage[p0] = (unsigned)r.x | (((unsigned)c.x & (BSZ - 1)) << 17);
            stage[p1] = (unsigned)r.y | (((unsigned)c.y & (BSZ - 1)) << 17);
            stage[p2] = (unsigned)r.z | (((unsigned)c.z & (BSZ - 1)) << 17);
            stage[p3] = (unsigned)r.w | (((unsigned)c.w & (BSZ - 1)) << 17);
        }
        for (int k = s + (nq << 2) + t; k < e; k += blockDim.x) {
            unsigned c = (unsigned)col[k];
            unsigned pos = atomicAdd(&lcur[c >> SHIFT], 1u);
            stage[pos] = (unsigned)row[k] | ((c & (BSZ - 1)) << 17);
        }
    }
    __syncthreads();
    // flush: per wave per bucket, consecutive lanes -> consecutive addresses
    int wid = t >> 6, lane = t & 63, nw = blockDim.x >> 6;
    for (int b = wid; b < nbuck; b += nw) {
        unsigned cntb = hA[b], lo = lofs[b], go = gbase[b];
        for (unsigned i = lane; i < cntb; i += 64)
            out[go + i] = stage[lo + i];
    }
}

// ---- 8-edge/thread accumulate helpers (MLP for latency-bound gathers) ----
__device__ __forceinline__ void accum_gather8(const unsigned* __restrict__ buck,
                                              unsigned s, unsigned e,
                                              const float* __restrict__ gin,
                                              float* __restrict__ acc) {
    unsigned sa = (s + 3u) & ~3u;
    if (sa > e) sa = e;
    if (s + threadIdx.x < sa) {
        unsigned w = buck[s + threadIdx.x];
        atomicAdd(&acc[w >> 17], gin[w & ROWMASK]);
    }
    unsigned nq  = (e - sa) >> 2;            // uint4 groups
    unsigned nq8 = nq >> 1;                  // pairs of uint4 = 8 edges
    const uint4* bq = (const uint4*)(buck + sa);
    for (unsigned q = threadIdx.x; q < nq8; q += blockDim.x) {
        uint4 w0 = bq[2 * q];
        uint4 w1 = bq[2 * q + 1];
        float a0 = gin[w0.x & ROWMASK];
        float a1 = gin[w0.y & ROWMASK];
        float a2 = gin[w0.z & ROWMASK];
        float a3 = gin[w0.w & ROWMASK];
        float a4 = gin[w1.x & ROWMASK];
        float a5 = gin[w1.y & ROWMASK];
        float a6 = gin[w1.z & ROWMASK];
        float a7 = gin[w1.w & ROWMASK];
        atomicAdd(&acc[w0.x >> 17], a0);
        atomicAdd(&acc[w0.y >> 17], a1);
        atomicAdd(&acc[w0.z >> 17], a2);
        atomicAdd(&acc[w0.w >> 17], a3);
        atomicAdd(&acc[w1.x >> 17], a4);
        atomicAdd(&acc[w1.y >> 17], a5);
        atomicAdd(&acc[w1.z >> 17], a6);
        atomicAdd(&acc[w1.w >> 17], a7);
    }
    // leftover uint4 (if nq odd)
    if ((nq & 1u) && threadIdx.x == 0) {
        uint4 w = bq[nq - 1];
        atomicAdd(&acc[w.x >> 17], gin[w.x & ROWMASK]);
        atomicAdd(&acc[w.y >> 17], gin[w.y & ROWMASK]);
        atomicAdd(&acc[w.z >> 17], gin[w.z & ROWMASK]);
        atomicAdd(&acc[w.w >> 17], gin[w.w & ROWMASK]);
    }
    for (unsigned k = sa + (nq << 2) + threadIdx.x; k < e; k += blockDim.x) {
        unsigned w = buck[k];
        atomicAdd(&acc[w >> 17], gin[w & ROWMASK]);
    }
}

__device__ __forceinline__ void accum_count8(const unsigned* __restrict__ buck,
                                             unsigned s, unsigned e,
                                             float* __restrict__ acc) {
    unsigned sa = (s + 3u) & ~3u;
    if (sa > e) sa = e;
    if (s + threadIdx.x < sa)
        atomicAdd(&acc[buck[s + threadIdx.x] >> 17], 1.0f);
    unsigned nq  = (e - sa) >> 2;
    unsigned nq8 = nq >> 1;
    const uint4* bq = (const uint4*)(buck + sa);
    for (unsigned q = threadIdx.x; q < nq8; q += blockDim.x) {
        uint4 w0 = bq[2 * q];
        uint4 w1 = bq[2 * q + 1];
        atomicAdd(&acc[w0.x >> 17], 1.0f);
        atomicAdd(&acc[w0.y >> 17], 1.0f);
        atomicAdd(&acc[w0.z >> 17], 1.0f);
        atomicAdd(&acc[w0.w >> 17], 1.0f);
        atomicAdd(&acc[w1.x >> 17], 1.0f);
        atomicAdd(&acc[w1.y >> 17], 1.0f);
        atomicAdd(&acc[w1.z >> 17], 1.0f);
        atomicAdd(&acc[w1.w >> 17], 1.0f);
    }
    if ((nq & 1u) && threadIdx.x == 0) {
        uint4 w = bq[nq - 1];
        atomicAdd(&acc[w.x >> 17], 1.0f);
        atomicAdd(&acc[w.y >> 17], 1.0f);
        atomicAdd(&acc[w.z >> 17], 1.0f);
        atomicAdd(&acc[w.w >> 17], 1.0f);
    }
    for (unsigned k = sa + (nq << 2) + threadIdx.x; k < e; k += blockDim.x)
        atomicAdd(&acc[buck[k] >> 17], 1.0f);
}

// ---- K4: degree count + node0 epilogue (dinv, g0 = dinv * x.u) ----
__global__ void degnode0_kernel(const unsigned* __restrict__ buck,
                                const unsigned* __restrict__ bstart,
                                const float* __restrict__ x, const float* __restrict__ coeff,
                                float* __restrict__ dinv, float* __restrict__ g, int n) {
    __shared__ float acc[BSZ];
    int b = blockIdx.x;
    if (threadIdx.x < BSZ) acc[threadIdx.x] = 0.f;
    __syncthreads();
    accum_count8(buck, bstart[b], bstart[b + 1], acc);
    __syncthreads();
    int node = b * BSZ + threadIdx.x;
    if (threadIdx.x < BSZ && node < n) {
        float d = rsqrtf(acc[threadIdx.x] + 1.0f);
        dinv[node] = d;
        float4 xv = ((const float4*)x)[node];
        float t0 = xv.x * coeff[0] + xv.y * coeff[1] + xv.z * coeff[2] + xv.w * coeff[3];
        g[node] = d * t0;
    }
}

// ---- K5/K6: gather pass with fused node epilogue ----
__global__ void gather_kernel(const unsigned* __restrict__ buck,
                              const unsigned* __restrict__ bstart,
                              const float* __restrict__ dinv, const float* __restrict__ gin,
                              float* __restrict__ gout, const float* __restrict__ coeff,
                              int sidx, int n) {
    __shared__ float acc[BSZ];
    int b = blockIdx.x;
    if (threadIdx.x < BSZ) acc[threadIdx.x] = 0.f;
    __syncthreads();
    accum_gather8(buck, bstart[b], bstart[b + 1], gin, acc);
    __syncthreads();
    int node = b * BSZ + threadIdx.x;
    if (threadIdx.x < BSZ && node < n) {
        float d = dinv[node];
        float t = d * (acc[threadIdx.x] + gin[node]) + coeff[sidx];
        gout[node] = d * t;
    }
}

// ---- K7: pass 3 gather + segmented mean-pool + last-block final ----
__global__ void gatherpool_kernel(const unsigned* __restrict__ buck,
                                  const unsigned* __restrict__ bstart,
                                  const float* __restrict__ dinv, const float* __restrict__ gin,
                                  const float* __restrict__ coeff, const int* __restrict__ batch,
                                  float* __restrict__ sums, float* __restrict__ cnt,
                                  float* __restrict__ out, int ngraphs,
                                  unsigned* __restrict__ done, int n) {
    __shared__ float acc[BSZ];
    __shared__ float ls[PSLOTS], lc[PSLOTS];
    __shared__ int bF;
    __shared__ unsigned lastFlag;
    int b = blockIdx.x;
    if (threadIdx.x < BSZ) acc[threadIdx.x] = 0.f;
    for (int i = threadIdx.x; i < PSLOTS; i += blockDim.x) { ls[i] = 0.f; lc[i] = 0.f; }
    if (threadIdx.x == 0) bF = batch[min(b * BSZ, n - 1)];
    __syncthreads();
    accum_gather8(buck, bstart[b], bstart[b + 1], gin, acc);
    __syncthreads();
    int node = b * BSZ + threadIdx.x;
    if (threadIdx.x < BSZ && node < n) {
        float d = dinv[node];
        float t3 = d * (acc[threadIdx.x] + gin[node]) + coeff[6];
        int rb = batch[node] - bF;               // batch sorted -> rb >= 0
        if (rb < PSLOTS) {
            atomicAdd(&ls[rb], t3);
            atomicAdd(&lc[rb], 1.0f);
        } else {
            atomicAdd(&sums[bF + rb], t3);
            atomicAdd(&cnt[bF + rb], 1.0f);
        }
    }
    __syncthreads();
    for (int i = threadIdx.x; i < PSLOTS; i += blockDim.x) {
        if (lc[i] != 0.f) {
            atomicAdd(&sums[bF + i], ls[i]);
            atomicAdd(&cnt[bF + i], lc[i]);
        }
    }
    // ---- last-block-done: final mean+bias+sigmoid ----
    __syncthreads();
    __threadfence();                              // release our sums/cnt atomics
    if (threadIdx.x == 0)
        lastFlag = (atomicAdd(done, 1u) == (unsigned)(gridDim.x - 1)) ? 1u : 0u;
    __syncthreads();
    if (lastFlag) {
        for (int i = threadIdx.x; i < ngraphs; i += blockDim.x) {
            float sv = atomicAdd(&sums[i], 0.f);  // coherent (coherence-point) reads
            float cv = atomicAdd(&cnt[i], 0.f);
            float m = sv / fmaxf(cv, 1.0f) + coeff[7];
            out[i] = 1.0f / (1.0f + expf(-m));
        }
    }
}

// ---- final (fallback path only) ----
__global__ void final_kernel(const float* __restrict__ sums, const float* __restrict__ cnt,
                             const float* __restrict__ coeff, float* __restrict__ out,
                             int ngraphs) {
    int i = blockIdx.x * blockDim.x + threadIdx.x;
    if (i < ngraphs) {
        float m = sums[i] / fmaxf(cnt[i], 1.0f) + coeff[7];
        out[i] = 1.0f / (1.0f + expf(-m));
    }
}

// ======================= fallback (R1 atomic path) =========================
__global__ void fb_coeffs_kernel(const float* __restrict__ W1, const float* __restrict__ b1,
                                 const float* __restrict__ W2, const float* __restrict__ b2,
                                 const float* __restrict__ W3, const float* __restrict__ b3,
                                 const float* __restrict__ lin_w, const float* __restrict__ lin_b,
                                 float* __restrict__ coeff,
                                 float* __restrict__ sums, float* __restrict__ cnt, int ngraphs) {
    for (int i = threadIdx.x; i < ngraphs; i += blockDim.x) { sums[i] = 0.f; cnt[i] = 0.f; }
    if (threadIdx.x == 0) {
        float w3l[16], w2l[16];
        for (int i = 0; i < 16; ++i) {
            float s = 0.f;
            for (int j = 0; j < 16; ++j) s += W3[i * 16 + j] * lin_w[j];
            w3l[i] = s;
        }
        for (int i = 0; i < 16; ++i) {
            float s = 0.f;
            for (int j = 0; j < 16; ++j) s += W2[i * 16 + j] * w3l[j];
            w2l[i] = s;
        }
        for (int i = 0; i < 4; ++i) {
            float s = 0.f;
            for (int j = 0; j < 16; ++j) s += W1[i * 16 + j] * w2l[j];
            coeff[i] = s;
        }
        float s2 = 0.f, s1 = 0.f, s0 = 0.f;
        for (int j = 0; j < 16; ++j) {
            s2 += b1[j] * w2l[j];
            s1 += b2[j] * w3l[j];
            s0 += b3[j] * lin_w[j];
        }
        coeff[4] = s2; coeff[5] = s1; coeff[6] = s0; coeff[7] = lin_b[0];
    }
}
__global__ void fb_init_kernel(float* __restrict__ deg, int n) {
    int i = blockIdx.x * blockDim.x + threadIdx.x;
    int stride = gridDim.x * blockDim.x;
    for (int k = i; k < n; k += stride) deg[k] = 1.0f;
}
__global__ void fb_deg_kernel(const int* __restrict__ col, float* __restrict__ deg, int E) {
    int i = blockIdx.x * blockDim.x + threadIdx.x;
    int stride = gridDim.x * blockDim.x;
    for (int k = i; k < E; k += stride) atomicAdd(&deg[col[k]], 1.0f);
}
__global__ void fb_node0_kernel(const float* __restrict__ x, const float* __restrict__ coeff,
                                float* __restrict__ deg_dinv, float* __restrict__ g,
                                float* __restrict__ acc, int n) {
    int i = blockIdx.x * blockDim.x + threadIdx.x;
    int stride = gridDim.x * blockDim.x;
    for (int k = i; k < n; k += stride) {
        float d = rsqrtf(deg_dinv[k]);
        deg_dinv[k] = d;
        float4 xv = ((const float4*)x)[k];
        float t0 = xv.x * coeff[0] + xv.y * coeff[1] + xv.z * coeff[2] + xv.w * coeff[3];
        g[k] = d * t0;
        acc[k] = 0.f;
    }
}
__global__ void fb_edge_kernel(const int* __restrict__ ei, const float* __restrict__ g,
                               float* __restrict__ acc, int E) {
    int i = blockIdx.x * blockDim.x + threadIdx.x;
    int stride = gridDim.x * blockDim.x;
    for (int k = i; k < E; k += stride) atomicAdd(&acc[ei[E + k]], g[ei[k]]);
}
__global__ void fb_node_kernel(const float* __restrict__ dinv, float* __restrict__ g,
                               float* __restrict__ acc, const float* __restrict__ coeff,
                               int sidx, int n) {
    int i = blockIdx.x * blockDim.x + threadIdx.x;
    int stride = gridDim.x * blockDim.x;
    for (int k = i; k < n; k += stride) {
        float d = dinv[k];
        float t = d * (acc[k] + g[k]) + coeff[sidx];
        g[k] = d * t;
        acc[k] = 0.f;
    }
}
__global__ void fb_pool_kernel(const float* __restrict__ dinv, const float* __restrict__ g,
                               const float* __restrict__ acc, const float* __restrict__ coeff,
                               const int* __restrict__ batch, float* __restrict__ sums,
                               float* __restrict__ cnt, int n) {
    int i = blockIdx.x * blockDim.x + threadIdx.x;
    int stride = gridDim.x * blockDim.x;
    for (int k = i; k < n; k += stride) {
        float d = dinv[k];
        float t3 = d * (acc[k] + g[k]) + coeff[6];
        int b = batch[k];
        atomicAdd(&sums[b], t3);
        atomicAdd(&cnt[b], 1.0f);
    }
}
// ===========================================================================

extern "C" void kernel_launch(void* const* d_in, const int* in_sizes, int n_in,
                              void* d_out, int out_size, void* d_ws, size_t ws_size,
                              hipStream_t stream) {
    const float* x     = (const float*)d_in[0];
    const int*   ei    = (const int*)d_in[1];
    const int*   batch = (const int*)d_in[2];
    const float* W1    = (const float*)d_in[3];
    const float* b1    = (const float*)d_in[4];
    const float* W2    = (const float*)d_in[5];
    const float* b2    = (const float*)d_in[6];
    const float* W3    = (const float*)d_in[7];
    const float* b3    = (const float*)d_in[8];
    const float* lin_w = (const float*)d_in[9];
    const float* lin_b = (const float*)d_in[10];

    const int n       = in_sizes[0] / 4;   // 100000
    const int E       = in_sizes[1] / 2;   // 3200000
    const int ngraphs = out_size;          // 1000

    const int nbuck = (n + BSZ - 1) / BSZ; // 391
    const int B = 256;

    size_t npad  = ((size_t)n + 255) & ~(size_t)255;
    size_t gpad  = ((size_t)ngraphs + 255) & ~(size_t)255;
    size_t nbpad = ((size_t)nbuck + 1 + 255) & ~(size_t)255;
    size_t mlen  = (size_t)NB_SCAT * nbuck;

    size_t need = (256 + 3 * mlen + 2 * nbpad + 256 + (size_t)E + 3 * npad + 2 * gpad) * 4;

    float* ws    = (float*)d_ws;
    float* coeff = ws;                                    // 256
    unsigned* Mcnt     = (unsigned*)(coeff + 256);        // mlen
    unsigned* Mloc     = Mcnt + mlen;                     // mlen
    unsigned* Mpre     = Mloc + mlen;                     // mlen
    unsigned* binTotal = Mpre + mlen;                     // nbpad
    unsigned* bstart   = binTotal + nbpad;                // nbpad
    unsigned* done     = bstart + nbpad;                  // 256 (1 used)
    unsigned* buck     = done + 256;                      // E (16B aligned)
    float* dinv  = (float*)(buck + E);                    // npad
    float* gA    = dinv + npad;                           // npad
    float* gB    = gA + npad;                             // npad
    float* sums  = gB + npad;                             // gpad
    float* cnt   = sums + gpad;                           // gpad

    int tile = (((E + NB_SCAT - 1) / NB_SCAT) + 3) & ~3;   // multiple of 4
    size_t ldsScat = (size_t)(4 * nbuck + B_SCAT + tile) * sizeof(unsigned);

    bool mainok = (n < (1 << 17)) && nbuck >= 1 && nbuck <= MAXNB &&
                  ws_size >= need && ldsScat <= 63 * 1024;

    if (!mainok) {
        // -------- fallback: R1 atomic path --------
        float* fcoeff = ws;
        float* deg = fcoeff + 256;
        float* g   = deg + npad;
        float* acc = g + npad;
        float* fsums = acc + npad;
        float* fcnt  = fsums + gpad;
        int nodeBlocks = (n + B - 1) / B;
        int edgeBlocks = (E + B - 1) / B;
        fb_coeffs_kernel<<<1, 64, 0, stream>>>(W1, b1, W2, b2, W3, b3, lin_w, lin_b, fcoeff,
                                               fsums, fcnt, ngraphs);
        fb_init_kernel<<<nodeBlocks, B, 0, stream>>>(deg, n);
        fb_deg_kernel<<<edgeBlocks, B, 0, stream>>>(ei + E, deg, E);
        fb_node0_kernel<<<nodeBlocks, B, 0, stream>>>(x, fcoeff, deg, g, acc, n);
        fb_edge_kernel<<<edgeBlocks, B, 0, stream>>>(ei, g, acc, E);
        fb_node_kernel<<<nodeBlocks, B, 0, stream>>>(deg, g, acc, fcoeff, 4, n);
        fb_edge_kernel<<<edgeBlocks, B, 0, stream>>>(ei, g, acc, E);
        fb_node_kernel<<<nodeBlocks, B, 0, stream>>>(deg, g, acc, fcoeff, 5, n);
        fb_edge_kernel<<<edgeBlocks, B, 0, stream>>>(ei, g, acc, E);
        fb_pool_kernel<<<nodeBlocks, B, 0, stream>>>(deg, g, acc, fcoeff, batch, fsums, fcnt, n);
        final_kernel<<<(ngraphs + B - 1) / B, B, 0, stream>>>(fsums, fcnt, fcoeff, (float*)d_out, ngraphs);
        return;
    }

    size_t ldsHist = (size_t)nbuck * sizeof(unsigned);

    hist_kernel<<<NB_SCAT, B_SCAT, ldsHist, stream>>>(ei + E, E, tile, nbuck, Mcnt, Mloc,
                                                      W1, b1, W2, b2, W3, b3, lin_w, lin_b,
                                                      coeff, sums, cnt, ngraphs, done);
    scanA_kernel<<<nbuck, NB_SCAT, 0, stream>>>(Mcnt, Mpre, binTotal, nbuck);
    scatter_kernel<<<NB_SCAT, B_SCAT, ldsScat, stream>>>(ei, ei + E, E, tile, nbuck,
                                                         Mcnt, Mloc, Mpre, binTotal,
                                                         bstart, buck);

    degnode0_kernel<<<nbuck, B_GATH, 0, stream>>>(buck, bstart, x, coeff, dinv, gA, n);
    gather_kernel<<<nbuck, B_GATH, 0, stream>>>(buck, bstart, dinv, gA, gB, coeff, 4, n);
    gather_kernel<<<nbuck, B_GATH, 0, stream>>>(buck, bstart, dinv, gB, gA, coeff, 5, n);
    gatherpool_kernel<<<nbuck, B_GATH, 0, stream>>>(buck, bstart, dinv, gA, coeff, batch,
                                                    sums, cnt, (float*)d_out, ngraphs,
                                                    done, n);
}

// Round 13
// 128.862 us; speedup vs baseline: 1.5988x; 1.5988x over previous
//
#include <hip/hip_runtime.h>
#include <math.h>

// ---------------------------------------------------------------------------
// GCN: 3x GCNConv (linear) -> mean pool -> linear -> sigmoid.
// Linear-collapse identity (absmax 0.0 through R12):
//   h3 @ lin_w = A(A(A(X u) + s2) + s1) + s0,  u = W1W2W3 lin_w.
// Hardware lessons (twice-confirmed): cross-XCD coherence primitives are
// ~50-100us-scale on MI355X (R10 grid.sync ~50us/sync; R12 per-thread
// __threadfence ~100us aggregate). The 1.6us dispatch boundary IS the cheap
// grid barrier. R13 = R11 structure (8 dispatches, plain final_kernel)
// + 8-edge/thread unroll in bucket passes (kept; harmless-to-positive).
// ---------------------------------------------------------------------------

#define SHIFT      8
#define BSZ        256         // nodes per bucket = 1<<SHIFT
#define NB_SCAT    256         // blocks for hist/scatter phases
#define B_SCAT     1024        // threads for hist/scatter
#define B_GATH     1024        // threads for bucket (gather) kernels
#define ROWMASK    0x1FFFFu    // 17 bits for row id (n < 131072)
#define PSLOTS     64          // LDS pool slots per pass-3 block
#define MAXNB      2048        // scan capacity guard

// ---- K1: histogram + in-block scan (Mcnt, Mloc) + coeffs + zero sums ----
__global__ void hist_kernel(const int* __restrict__ col, int E, int tile, int nbuck,
                            unsigned* __restrict__ Mcnt, unsigned* __restrict__ Mloc,
                            const float* __restrict__ W1, const float* __restrict__ b1,
                            const float* __restrict__ W2, const float* __restrict__ b2,
                            const float* __restrict__ W3, const float* __restrict__ b3,
                            const float* __restrict__ lin_w, const float* __restrict__ lin_b,
                            float* __restrict__ coeff,
                            float* __restrict__ sums, float* __restrict__ cnt, int ngraphs) {
    extern __shared__ unsigned h[];
    __shared__ unsigned tsum[B_SCAT];
    __shared__ float w3l[16], w2l[16];
    int t = threadIdx.x;
    for (int i = t; i < nbuck; i += blockDim.x) h[i] = 0;
    if (blockIdx.x == 0) {
        for (int i = t; i < ngraphs; i += blockDim.x) { sums[i] = 0.f; cnt[i] = 0.f; }
        if (t < 16) {
            float s = 0.f;
            for (int j = 0; j < 16; ++j) s += W3[t * 16 + j] * lin_w[j];
            w3l[t] = s;
        }
    }
    __syncthreads();
    if (blockIdx.x == 0 && t < 16) {
        float s = 0.f;
        for (int j = 0; j < 16; ++j) s += W2[t * 16 + j] * w3l[j];
        w2l[t] = s;
    }
    __syncthreads();
    if (blockIdx.x == 0) {
        if (t < 4) {
            float s = 0.f;
            for (int j = 0; j < 16; ++j) s += W1[t * 16 + j] * w2l[j];
            coeff[t] = s;
        } else if (t == 4) {
            float s = 0.f;
            for (int j = 0; j < 16; ++j) s += b1[j] * w2l[j];
            coeff[4] = s;
        } else if (t == 5) {
            float s = 0.f;
            for (int j = 0; j < 16; ++j) s += b2[j] * w3l[j];
            coeff[5] = s;
        } else if (t == 6) {
            float s = 0.f;
            for (int j = 0; j < 16; ++j) s += b3[j] * lin_w[j];
            coeff[6] = s;
        } else if (t == 7) {
            coeff[7] = lin_b[0];
        }
    }
    // histogram of this block's tile
    int b = blockIdx.x;
    int s = b * tile, e = min(s + tile, E);          // s multiple of 4
    if (s < e) {
        int nq = (e - s) >> 2;
        const int4* c4 = (const int4*)(col + s);
        for (int q = t; q < nq; q += blockDim.x) {
            int4 c = c4[q];
            atomicAdd(&h[((unsigned)c.x) >> SHIFT], 1u);
            atomicAdd(&h[((unsigned)c.y) >> SHIFT], 1u);
            atomicAdd(&h[((unsigned)c.z) >> SHIFT], 1u);
            atomicAdd(&h[((unsigned)c.w) >> SHIFT], 1u);
        }
        for (int k = s + (nq << 2) + t; k < e; k += blockDim.x)
            atomicAdd(&h[((unsigned)col[k]) >> SHIFT], 1u);
    }
    __syncthreads();
    // in-block exclusive scan of h -> Mloc; counts -> Mcnt
    const int C = MAXNB / B_SCAT;            // 2 elems/thread
    unsigned lv[C];
    unsigned run = 0;
    for (int k = 0; k < C; ++k) {
        int i = t * C + k;
        unsigned x = (i < nbuck) ? h[i] : 0u;
        lv[k] = run; run += x;
    }
    tsum[t] = run;
    __syncthreads();
    for (int off = 1; off < B_SCAT; off <<= 1) {
        unsigned u = (t >= off) ? tsum[t - off] : 0u;
        __syncthreads();
        tsum[t] += u;
        __syncthreads();
    }
    unsigned ex = (t == 0) ? 0u : tsum[t - 1];
    for (int k = 0; k < C; ++k) {
        int i = t * C + k;
        if (i < nbuck) {
            Mcnt[(size_t)b * nbuck + i] = h[i];
            Mloc[(size_t)b * nbuck + i] = ex + lv[k];
        }
    }
}

// ---- K2: per-bin exclusive scan over block counts -> Mpre, binTotal ----
__global__ void scanA_kernel(const unsigned* __restrict__ Mcnt, unsigned* __restrict__ Mpre,
                             unsigned* __restrict__ binTotal, int nbuck) {
    __shared__ unsigned sc[NB_SCAT];
    int b = blockIdx.x;
    int t = threadIdx.x;
    unsigned v = Mcnt[(size_t)t * nbuck + b];
    sc[t] = v;
    __syncthreads();
    for (int off = 1; off < NB_SCAT; off <<= 1) {
        unsigned u = (t >= off) ? sc[t - off] : 0u;
        __syncthreads();
        sc[t] += u;
        __syncthreads();
    }
    Mpre[(size_t)t * nbuck + b] = sc[t] - v;     // exclusive within bin
    if (t == NB_SCAT - 1) binTotal[b] = sc[t];
}

// ---- K3: scatter; tables preloaded, only binTotal scan in-block ----
// pack: row(17b) | col_low(8b)<<17
__global__ void scatter_kernel(const int* __restrict__ row, const int* __restrict__ col,
                               int E, int tile, int nbuck,
                               const unsigned* __restrict__ Mcnt,
                               const unsigned* __restrict__ Mloc,
                               const unsigned* __restrict__ Mpre,
                               const unsigned* __restrict__ binTotal,
                               unsigned* __restrict__ bstart,
                               unsigned* __restrict__ out) {
    extern __shared__ unsigned lds[];
    unsigned* hA    = lds;                   // nbuck  local counts
    unsigned* lofs  = lds + nbuck;           // nbuck  local exclusive offsets
    unsigned* lcur  = lds + 2 * nbuck;       // nbuck  placement cursors
    unsigned* gbase = lds + 3 * nbuck;       // nbuck  global run starts (this block)
    unsigned* tsum  = lds + 4 * nbuck;       // B_SCAT scan workspace
    unsigned* stage = lds + 4 * nbuck + B_SCAT; // tile staged packed words
    int t = threadIdx.x, j = blockIdx.x;
    // load local tables
    for (int i = t; i < nbuck; i += blockDim.x) {
        unsigned c = Mcnt[(size_t)j * nbuck + i];
        unsigned l = Mloc[(size_t)j * nbuck + i];
        hA[i] = c; lofs[i] = l; lcur[i] = l;
    }
    // binTotal exclusive scan -> gbase (+ bstart publish from block 0)
    const int C = MAXNB / B_SCAT;            // 2 elems/thread
    unsigned lv[C];
    unsigned run = 0;
    for (int k = 0; k < C; ++k) {
        int i = t * C + k;
        unsigned x = (i < nbuck) ? binTotal[i] : 0u;
        lv[k] = run; run += x;
    }
    tsum[t] = run;
    __syncthreads();
    for (int off = 1; off < B_SCAT; off <<= 1) {
        unsigned u = (t >= off) ? tsum[t - off] : 0u;
        __syncthreads();
        tsum[t] += u;
        __syncthreads();
    }
    unsigned ex = (t == 0) ? 0u : tsum[t - 1];
    for (int k = 0; k < C; ++k) {
        int i = t * C + k;
        if (i < nbuck) {
            unsigned bb = ex + lv[k];
            gbase[i] = bb + Mpre[(size_t)j * nbuck + i];
            if (j == 0) bstart[i] = bb;
        }
    }
    if (j == 0 && t == 0) bstart[nbuck] = (unsigned)E;
    __syncthreads();
    // placement into stage (LDS random write)
    int s = j * tile, e = min(s + tile, E);
    if (s < e) {
        int nq = (e - s) >> 2;
        const int4* r4 = (const int4*)(row + s);
        const int4* c4 = (const int4*)(col + s);
        for (int q = t; q < nq; q += blockDim.x) {
            int4 r = r4[q];
            int4 c = c4[q];
            unsigned p0 = atomicAdd(&lcur[((unsigned)c.x) >> SHIFT], 1u);
            unsigned p1 = atomicAdd(&lcur[((unsigned)c.y) >> SHIFT], 1u);
            unsigned p2 = atomicAdd(&lcur[((unsigned)c.z) >> SHIFT], 1u);
            unsigned p3 = atomicAdd(&lcur[((unsigned)c.w) >> SHIFT], 1u);
            stage[p0] = (unsigned)r.x | (((unsigned)c.x & (BSZ - 1)) << 17);
            stage[p1] = (unsigned)r.y | (((unsigned)c.y & (BSZ - 1)) << 17);
            stage[p2] = (unsigned)r.z | (((unsigned)c.z & (BSZ - 1)) << 17);
            stage[p3] = (unsigned)r.w | (((unsigned)c.w & (BSZ - 1)) << 17);
        }
        for (int k = s + (nq << 2) + t; k < e; k += blockDim.x) {
            unsigned c = (unsigned)col[k];
            unsigned pos = atomicAdd(&lcur[c >> SHIFT], 1u);
            stage[pos] = (unsigned)row[k] | ((c & (BSZ - 1)) << 17);
        }
    }
    __syncthreads();
    // flush: per wave per bucket, consecutive lanes -> consecutive addresses
    int wid = t >> 6, lane = t & 63, nw = blockDim.x >> 6;
    for (int b = wid; b < nbuck; b += nw) {
        unsigned cntb = hA[b], lo = lofs[b], go = gbase[b];
        for (unsigned i = lane; i < cntb; i += 64)
            out[go + i] = stage[lo + i];
    }
}

// ---- 8-edge/thread accumulate helpers (MLP for latency-bound gathers) ----
__device__ __forceinline__ void accum_gather8(const unsigned* __restrict__ buck,
                                              unsigned s, unsigned e,
                                              const float* __restrict__ gin,
                                              float* __restrict__ acc) {
    unsigned sa = (s + 3u) & ~3u;
    if (sa > e) sa = e;
    if (s + threadIdx.x < sa) {
        unsigned w = buck[s + threadIdx.x];
        atomicAdd(&acc[w >> 17], gin[w & ROWMASK]);
    }
    unsigned nq  = (e - sa) >> 2;            // uint4 groups
    unsigned nq8 = nq >> 1;                  // pairs of uint4 = 8 edges
    const uint4* bq = (const uint4*)(buck + sa);
    for (unsigned q = threadIdx.x; q < nq8; q += blockDim.x) {
        uint4 w0 = bq[2 * q];
        uint4 w1 = bq[2 * q + 1];
        float a0 = gin[w0.x & ROWMASK];
        float a1 = gin[w0.y & ROWMASK];
        float a2 = gin[w0.z & ROWMASK];
        float a3 = gin[w0.w & ROWMASK];
        float a4 = gin[w1.x & ROWMASK];
        float a5 = gin[w1.y & ROWMASK];
        float a6 = gin[w1.z & ROWMASK];
        float a7 = gin[w1.w & ROWMASK];
        atomicAdd(&acc[w0.x >> 17], a0);
        atomicAdd(&acc[w0.y >> 17], a1);
        atomicAdd(&acc[w0.z >> 17], a2);
        atomicAdd(&acc[w0.w >> 17], a3);
        atomicAdd(&acc[w1.x >> 17], a4);
        atomicAdd(&acc[w1.y >> 17], a5);
        atomicAdd(&acc[w1.z >> 17], a6);
        atomicAdd(&acc[w1.w >> 17], a7);
    }
    if ((nq & 1u) && threadIdx.x == 0) {
        uint4 w = bq[nq - 1];
        atomicAdd(&acc[w.x >> 17], gin[w.x & ROWMASK]);
        atomicAdd(&acc[w.y >> 17], gin[w.y & ROWMASK]);
        atomicAdd(&acc[w.z >> 17], gin[w.z & ROWMASK]);
        atomicAdd(&acc[w.w >> 17], gin[w.w & ROWMASK]);
    }
    for (unsigned k = sa + (nq << 2) + threadIdx.x; k < e; k += blockDim.x) {
        unsigned w = buck[k];
        atomicAdd(&acc[w >> 17], gin[w & ROWMASK]);
    }
}

__device__ __forceinline__ void accum_count8(const unsigned* __restrict__ buck,
                                             unsigned s, unsigned e,
                                             float* __restrict__ acc) {
    unsigned sa = (s + 3u) & ~3u;
    if (sa > e) sa = e;
    if (s + threadIdx.x < sa)
        atomicAdd(&acc[buck[s + threadIdx.x] >> 17], 1.0f);
    unsigned nq  = (e - sa) >> 2;
    unsigned nq8 = nq >> 1;
    const uint4* bq = (const uint4*)(buck + sa);
    for (unsigned q = threadIdx.x; q < nq8; q += blockDim.x) {
        uint4 w0 = bq[2 * q];
        uint4 w1 = bq[2 * q + 1];
        atomicAdd(&acc[w0.x >> 17], 1.0f);
        atomicAdd(&acc[w0.y >> 17], 1.0f);
        atomicAdd(&acc[w0.z >> 17], 1.0f);
        atomicAdd(&acc[w0.w >> 17], 1.0f);
        atomicAdd(&acc[w1.x >> 17], 1.0f);
        atomicAdd(&acc[w1.y >> 17], 1.0f);
        atomicAdd(&acc[w1.z >> 17], 1.0f);
        atomicAdd(&acc[w1.w >> 17], 1.0f);
    }
    if ((nq & 1u) && threadIdx.x == 0) {
        uint4 w = bq[nq - 1];
        atomicAdd(&acc[w.x >> 17], 1.0f);
        atomicAdd(&acc[w.y >> 17], 1.0f);
        atomicAdd(&acc[w.z >> 17], 1.0f);
        atomicAdd(&acc[w.w >> 17], 1.0f);
    }
    for (unsigned k = sa + (nq << 2) + threadIdx.x; k < e; k += blockDim.x)
        atomicAdd(&acc[buck[k] >> 17], 1.0f);
}

// ---- K4: degree count + node0 epilogue (dinv, g0 = dinv * x.u) ----
__global__ void degnode0_kernel(const unsigned* __restrict__ buck,
                                const unsigned* __restrict__ bstart,
                                const float* __restrict__ x, const float* __restrict__ coeff,
                                float* __restrict__ dinv, float* __restrict__ g, int n) {
    __shared__ float acc[BSZ];
    int b = blockIdx.x;
    if (threadIdx.x < BSZ) acc[threadIdx.x] = 0.f;
    __syncthreads();
    accum_count8(buck, bstart[b], bstart[b + 1], acc);
    __syncthreads();
    int node = b * BSZ + threadIdx.x;
    if (threadIdx.x < BSZ && node < n) {
        float d = rsqrtf(acc[threadIdx.x] + 1.0f);
        dinv[node] = d;
        float4 xv = ((const float4*)x)[node];
        float t0 = xv.x * coeff[0] + xv.y * coeff[1] + xv.z * coeff[2] + xv.w * coeff[3];
        g[node] = d * t0;
    }
}

// ---- K5/K6: gather pass with fused node epilogue ----
__global__ void gather_kernel(const unsigned* __restrict__ buck,
                              const unsigned* __restrict__ bstart,
                              const float* __restrict__ dinv, const float* __restrict__ gin,
                              float* __restrict__ gout, const float* __restrict__ coeff,
                              int sidx, int n) {
    __shared__ float acc[BSZ];
    int b = blockIdx.x;
    if (threadIdx.x < BSZ) acc[threadIdx.x] = 0.f;
    __syncthreads();
    accum_gather8(buck, bstart[b], bstart[b + 1], gin, acc);
    __syncthreads();
    int node = b * BSZ + threadIdx.x;
    if (threadIdx.x < BSZ && node < n) {
        float d = dinv[node];
        float t = d * (acc[threadIdx.x] + gin[node]) + coeff[sidx];
        gout[node] = d * t;
    }
}

// ---- K7: pass 3 gather + fused segmented mean-pool (batch sorted) ----
__global__ void gatherpool_kernel(const unsigned* __restrict__ buck,
                                  const unsigned* __restrict__ bstart,
                                  const float* __restrict__ dinv, const float* __restrict__ gin,
                                  const float* __restrict__ coeff, const int* __restrict__ batch,
                                  float* __restrict__ sums, float* __restrict__ cnt, int n) {
    __shared__ float acc[BSZ];
    __shared__ float ls[PSLOTS], lc[PSLOTS];
    __shared__ int bF;
    int b = blockIdx.x;
    if (threadIdx.x < BSZ) acc[threadIdx.x] = 0.f;
    for (int i = threadIdx.x; i < PSLOTS; i += blockDim.x) { ls[i] = 0.f; lc[i] = 0.f; }
    if (threadIdx.x == 0) bF = batch[min(b * BSZ, n - 1)];
    __syncthreads();
    accum_gather8(buck, bstart[b], bstart[b + 1], gin, acc);
    __syncthreads();
    int node = b * BSZ + threadIdx.x;
    if (threadIdx.x < BSZ && node < n) {
        float d = dinv[node];
        float t3 = d * (acc[threadIdx.x] + gin[node]) + coeff[6];
        int rb = batch[node] - bF;               // batch sorted -> rb >= 0
        if (rb < PSLOTS) {
            atomicAdd(&ls[rb], t3);
            atomicAdd(&lc[rb], 1.0f);
        } else {
            atomicAdd(&sums[bF + rb], t3);
            atomicAdd(&cnt[bF + rb], 1.0f);
        }
    }
    __syncthreads();
    for (int i = threadIdx.x; i < PSLOTS; i += blockDim.x) {
        if (lc[i] != 0.f) {
            atomicAdd(&sums[bF + i], ls[i]);
            atomicAdd(&cnt[bF + i], lc[i]);
        }
    }
}

// ---- K8: mean + linear bias + sigmoid ----
__global__ void final_kernel(const float* __restrict__ sums, const float* __restrict__ cnt,
                             const float* __restrict__ coeff, float* __restrict__ out,
                             int ngraphs) {
    int i = blockIdx.x * blockDim.x + threadIdx.x;
    if (i < ngraphs) {
        float m = sums[i] / fmaxf(cnt[i], 1.0f) + coeff[7];
        out[i] = 1.0f / (1.0f + expf(-m));
    }
}

// ======================= fallback (R1 atomic path) =========================
__global__ void fb_coeffs_kernel(const float* __restrict__ W1, const float* __restrict__ b1,
                                 const float* __restrict__ W2, const float* __restrict__ b2,
                                 const float* __restrict__ W3, const float* __restrict__ b3,
                                 const float* __restrict__ lin_w, const float* __restrict__ lin_b,
                                 float* __restrict__ coeff,
                                 float* __restrict__ sums, float* __restrict__ cnt, int ngraphs) {
    for (int i = threadIdx.x; i < ngraphs; i += blockDim.x) { sums[i] = 0.f; cnt[i] = 0.f; }
    if (threadIdx.x == 0) {
        float w3l[16], w2l[16];
        for (int i = 0; i < 16; ++i) {
            float s = 0.f;
            for (int j = 0; j < 16; ++j) s += W3[i * 16 + j] * lin_w[j];
            w3l[i] = s;
        }
        for (int i = 0; i < 16; ++i) {
            float s = 0.f;
            for (int j = 0; j < 16; ++j) s += W2[i * 16 + j] * w3l[j];
            w2l[i] = s;
        }
        for (int i = 0; i < 4; ++i) {
            float s = 0.f;
            for (int j = 0; j < 16; ++j) s += W1[i * 16 + j] * w2l[j];
            coeff[i] = s;
        }
        float s2 = 0.f, s1 = 0.f, s0 = 0.f;
        for (int j = 0; j < 16; ++j) {
            s2 += b1[j] * w2l[j];
            s1 += b2[j] * w3l[j];
            s0 += b3[j] * lin_w[j];
        }
        coeff[4] = s2; coeff[5] = s1; coeff[6] = s0; coeff[7] = lin_b[0];
    }
}
__global__ void fb_init_kernel(float* __restrict__ deg, int n) {
    int i = blockIdx.x * blockDim.x + threadIdx.x;
    int stride = gridDim.x * blockDim.x;
    for (int k = i; k < n; k += stride) deg[k] = 1.0f;
}
__global__ void fb_deg_kernel(const int* __restrict__ col, float* __restrict__ deg, int E) {
    int i = blockIdx.x * blockDim.x + threadIdx.x;
    int stride = gridDim.x * blockDim.x;
    for (int k = i; k < E; k += stride) atomicAdd(&deg[col[k]], 1.0f);
}
__global__ void fb_node0_kernel(const float* __restrict__ x, const float* __restrict__ coeff,
                                float* __restrict__ deg_dinv, float* __restrict__ g,
                                float* __restrict__ acc, int n) {
    int i = blockIdx.x * blockDim.x + threadIdx.x;
    int stride = gridDim.x * blockDim.x;
    for (int k = i; k < n; k += stride) {
        float d = rsqrtf(deg_dinv[k]);
        deg_dinv[k] = d;
        float4 xv = ((const float4*)x)[k];
        float t0 = xv.x * coeff[0] + xv.y * coeff[1] + xv.z * coeff[2] + xv.w * coeff[3];
        g[k] = d * t0;
        acc[k] = 0.f;
    }
}
__global__ void fb_edge_kernel(const int* __restrict__ ei, const float* __restrict__ g,
                               float* __restrict__ acc, int E) {
    int i = blockIdx.x * blockDim.x + threadIdx.x;
    int stride = gridDim.x * blockDim.x;
    for (int k = i; k < E; k += stride) atomicAdd(&acc[ei[E + k]], g[ei[k]]);
}
__global__ void fb_node_kernel(const float* __restrict__ dinv, float* __restrict__ g,
                               float* __restrict__ acc, const float* __restrict__ coeff,
                               int sidx, int n) {
    int i = blockIdx.x * blockDim.x + threadIdx.x;
    int stride = gridDim.x * blockDim.x;
    for (int k = i; k < n; k += stride) {
        float d = dinv[k];
        float t = d * (acc[k] + g[k]) + coeff[sidx];
        g[k] = d * t;
        acc[k] = 0.f;
    }
}
__global__ void fb_pool_kernel(const float* __restrict__ dinv, const float* __restrict__ g,
                               const float* __restrict__ acc, const float* __restrict__ coeff,
                               const int* __restrict__ batch, float* __restrict__ sums,
                               float* __restrict__ cnt, int n) {
    int i = blockIdx.x * blockDim.x + threadIdx.x;
    int stride = gridDim.x * blockDim.x;
    for (int k = i; k < n; k += stride) {
        float d = dinv[k];
        float t3 = d * (acc[k] + g[k]) + coeff[6];
        int b = batch[k];
        atomicAdd(&sums[b], t3);
        atomicAdd(&cnt[b], 1.0f);
    }
}
// ===========================================================================

extern "C" void kernel_launch(void* const* d_in, const int* in_sizes, int n_in,
                              void* d_out, int out_size, void* d_ws, size_t ws_size,
                              hipStream_t stream) {
    const float* x     = (const float*)d_in[0];
    const int*   ei    = (const int*)d_in[1];
    const int*   batch = (const int*)d_in[2];
    const float* W1    = (const float*)d_in[3];
    const float* b1    = (const float*)d_in[4];
    const float* W2    = (const float*)d_in[5];
    const float* b2    = (const float*)d_in[6];
    const float* W3    = (const float*)d_in[7];
    const float* b3    = (const float*)d_in[8];
    const float* lin_w = (const float*)d_in[9];
    const float* lin_b = (const float*)d_in[10];

    const int n       = in_sizes[0] / 4;   // 100000
    const int E       = in_sizes[1] / 2;   // 3200000
    const int ngraphs = out_size;          // 1000

    const int nbuck = (n + BSZ - 1) / BSZ; // 391
    const int B = 256;

    size_t npad  = ((size_t)n + 255) & ~(size_t)255;
    size_t gpad  = ((size_t)ngraphs + 255) & ~(size_t)255;
    size_t nbpad = ((size_t)nbuck + 1 + 255) & ~(size_t)255;
    size_t mlen  = (size_t)NB_SCAT * nbuck;

    size_t need = (256 + 3 * mlen + 2 * nbpad + (size_t)E + 3 * npad + 2 * gpad) * 4;

    float* ws    = (float*)d_ws;
    float* coeff = ws;                                    // 256
    unsigned* Mcnt     = (unsigned*)(coeff + 256);        // mlen
    unsigned* Mloc     = Mcnt + mlen;                     // mlen
    unsigned* Mpre     = Mloc + mlen;                     // mlen
    unsigned* binTotal = Mpre + mlen;                     // nbpad
    unsigned* bstart   = binTotal + nbpad;                // nbpad
    unsigned* buck     = bstart + nbpad;                  // E (16B aligned)
    float* dinv  = (float*)(buck + E);                    // npad
    float* gA    = dinv + npad;                           // npad
    float* gB    = gA + npad;                             // npad
    float* sums  = gB + npad;                             // gpad
    float* cnt   = sums + gpad;                           // gpad

    int tile = (((E + NB_SCAT - 1) / NB_SCAT) + 3) & ~3;   // multiple of 4
    size_t ldsScat = (size_t)(4 * nbuck + B_SCAT + tile) * sizeof(unsigned);

    bool mainok = (n < (1 << 17)) && nbuck >= 1 && nbuck <= MAXNB &&
                  ws_size >= need && ldsScat <= 63 * 1024;

    if (!mainok) {
        // -------- fallback: R1 atomic path --------
        float* fcoeff = ws;
        float* deg = fcoeff + 256;
        float* g   = deg + npad;
        float* acc = g + npad;
        float* fsums = acc + npad;
        float* fcnt  = fsums + gpad;
        int nodeBlocks = (n + B - 1) / B;
        int edgeBlocks = (E + B - 1) / B;
        fb_coeffs_kernel<<<1, 64, 0, stream>>>(W1, b1, W2, b2, W3, b3, lin_w, lin_b, fcoeff,
                                               fsums, fcnt, ngraphs);
        fb_init_kernel<<<nodeBlocks, B, 0, stream>>>(deg, n);
        fb_deg_kernel<<<edgeBlocks, B, 0, stream>>>(ei + E, deg, E);
        fb_node0_kernel<<<nodeBlocks, B, 0, stream>>>(x, fcoeff, deg, g, acc, n);
        fb_edge_kernel<<<edgeBlocks, B, 0, stream>>>(ei, g, acc, E);
        fb_node_kernel<<<nodeBlocks, B, 0, stream>>>(deg, g, acc, fcoeff, 4, n);
        fb_edge_kernel<<<edgeBlocks, B, 0, stream>>>(ei, g, acc, E);
        fb_node_kernel<<<nodeBlocks, B, 0, stream>>>(deg, g, acc, fcoeff, 5, n);
        fb_edge_kernel<<<edgeBlocks, B, 0, stream>>>(ei, g, acc, E);
        fb_pool_kernel<<<nodeBlocks, B, 0, stream>>>(deg, g, acc, fcoeff, batch, fsums, fcnt, n);
        final_kernel<<<(ngraphs + B - 1) / B, B, 0, stream>>>(fsums, fcnt, fcoeff, (float*)d_out, ngraphs);
        return;
    }

    size_t ldsHist = (size_t)nbuck * sizeof(unsigned);

    hist_kernel<<<NB_SCAT, B_SCAT, ldsHist, stream>>>(ei + E, E, tile, nbuck, Mcnt, Mloc,
                                                      W1, b1, W2, b2, W3, b3, lin_w, lin_b,
                                                      coeff, sums, cnt, ngraphs);
    scanA_kernel<<<nbuck, NB_SCAT, 0, stream>>>(Mcnt, Mpre, binTotal, nbuck);
    scatter_kernel<<<NB_SCAT, B_SCAT, ldsScat, stream>>>(ei, ei + E, E, tile, nbuck,
                                                         Mcnt, Mloc, Mpre, binTotal,
                                                         bstart, buck);

    degnode0_kernel<<<nbuck, B_GATH, 0, stream>>>(buck, bstart, x, coeff, dinv, gA, n);
    gather_kernel<<<nbuck, B_GATH, 0, stream>>>(buck, bstart, dinv, gA, gB, coeff, 4, n);
    gather_kernel<<<nbuck, B_GATH, 0, stream>>>(buck, bstart, dinv, gB, gA, coeff, 5, n);
    gatherpool_kernel<<<nbuck, B_GATH, 0, stream>>>(buck, bstart, dinv, gA, coeff, batch,
                                                    sums, cnt, n);

    final_kernel<<<(ngraphs + B - 1) / B, B, 0, stream>>>(sums, cnt, coeff, (float*)d_out, ngraphs);
}